// Round 1
// baseline (22997.032 us; speedup 1.0000x reference)
//
#include <hip/hip_runtime.h>
#include <hip/hip_bf16.h>
#include <stdint.h>
#include <stddef.h>

// Problem constants
#define B_ 32
#define S_ 128
#define T_ 128
#define H_ 512
#define V_ 32000

typedef __bf16 bf16;
typedef __attribute__((ext_vector_type(8))) __bf16 bf16x8;
typedef __attribute__((ext_vector_type(4))) float f32x4;

#define AS1 __attribute__((address_space(1)))
#define AS3 __attribute__((address_space(3)))

__device__ __forceinline__ void load16_to_lds(const void* g, void* l) {
  __builtin_amdgcn_global_load_lds((AS1 void*)g, (AS3 void*)l, 16, 0, 0);
}

// ---------------------------------------------------------------------------
// Small utility kernels
// ---------------------------------------------------------------------------
__global__ void cvt_bf16(const float* __restrict__ in, bf16* __restrict__ out, int n) {
  int i = (blockIdx.x * 256 + threadIdx.x) * 4;
  if (i + 3 < n) {
    float4 v = *(const float4*)(in + i);
    out[i + 0] = (bf16)v.x; out[i + 1] = (bf16)v.y;
    out[i + 2] = (bf16)v.z; out[i + 3] = (bf16)v.w;
  }
}

// WattnT[n][j] = W_attn[j][n]  (512x512)
__global__ void transpose_cvt(const float* __restrict__ in, bf16* __restrict__ out) {
  int idx = blockIdx.x * 256 + threadIdx.x;
  int n = idx >> 9, j = idx & 511;
  out[idx] = (bf16)in[j * 512 + n];
}

// X[b*T+t][k] = embedding[dec_in(b,t)][k], dec_in = BOS(=1) then targets[:, :-1]
__global__ void gather_emb(const float* __restrict__ emb, const int* __restrict__ tgt,
                           bf16* __restrict__ X) {
  int row = blockIdx.x;
  int b = row >> 7, t = row & 127;
  int tok = (t == 0) ? 1 : tgt[b * T_ + t - 1];
  const float* src = emb + (size_t)tok * H_;
  bf16* dst = X + (size_t)row * H_;
  for (int k = threadIdx.x; k < H_; k += blockDim.x) dst[k] = (bf16)src[k];
}

// ---------------------------------------------------------------------------
// Generic bf16 GEMM:  C[M,N](f32) = A[M,K](bf16,lda) @ B^T  with B[N,K](bf16,ldb)
// + optional bias[N].  M%128==0, N%128==0, K%32==0.  grid=(N/128, M/128), 256 thr.
// m97-style: 128x128 tile, BK=32, global_load_lds width 16, 16x16x32 MFMA.
// ---------------------------------------------------------------------------
__launch_bounds__(256)
__global__ void gemm_bt(const bf16* __restrict__ A, int lda,
                        const bf16* __restrict__ Bm, int ldb,
                        float* __restrict__ C, int ldc,
                        const float* __restrict__ bias, int K) {
  __shared__ bf16 As[128 * 32];
  __shared__ bf16 Bs[128 * 32];
  const int m0 = blockIdx.y * 128, n0 = blockIdx.x * 128;
  const int tid = threadIdx.x, lane = tid & 63, wv = tid >> 6;
  const int wm = (wv >> 1) * 64, wn = (wv & 1) * 64;
  f32x4 acc[4][4] = {};

  for (int kt = 0; kt < K; kt += 32) {
    // stage A-tile and B-tile (each thread: 2+2 16B direct-to-LDS loads)
    for (int i = 0; i < 2; ++i) {
      int lin = i * 256 + tid;
      int row = lin >> 2;
      int c8  = (lin & 3) * 8;                       // element offset in k
      const bf16* ga = A  + (size_t)(m0 + row) * lda + kt + c8;
      const bf16* gb = Bm + (size_t)(n0 + row) * ldb + kt + c8;
      load16_to_lds(ga, (char*)As + i * 4096 + wv * 1024);
      load16_to_lds(gb, (char*)Bs + i * 4096 + wv * 1024);
    }
    __builtin_amdgcn_s_waitcnt(0);
    __syncthreads();

    bf16x8 af[4], bfr[4];
    int mrow = lane & 15, qd = lane >> 4;
    for (int i = 0; i < 4; ++i)
      af[i] = *(const bf16x8*)&As[(wm + i * 16 + mrow) * 32 + qd * 8];
    for (int i = 0; i < 4; ++i)
      bfr[i] = *(const bf16x8*)&Bs[(wn + i * 16 + mrow) * 32 + qd * 8];
    for (int mi = 0; mi < 4; ++mi)
      for (int ni = 0; ni < 4; ++ni)
        acc[mi][ni] = __builtin_amdgcn_mfma_f32_16x16x32_bf16(af[mi], bfr[ni], acc[mi][ni], 0, 0, 0);
    __syncthreads();
  }

  int qd = lane >> 4;
  for (int mi = 0; mi < 4; ++mi)
    for (int ni = 0; ni < 4; ++ni) {
      int rbase = m0 + wm + mi * 16 + qd * 4;
      int col   = n0 + wn + ni * 16 + (lane & 15);
      float bv = bias ? bias[col] : 0.f;
      for (int r = 0; r < 4; ++r)
        C[(size_t)(rbase + r) * ldc + col] = acc[mi][ni][r] + bv;
    }
}

// ---------------------------------------------------------------------------
// Persistent sequential decoder kernel. 256 blocks x 256 threads, 1 block/CU
// (134 KB LDS).  Blocks 0..127: attention (b = bi>>2, quarter q = bi&3),
// blocks 128..255: gate slice g (4 h-dims each, all 32 batches via MFMA).
// 2 custom grid syncs per step.
// ---------------------------------------------------------------------------
__device__ __forceinline__ void gsync(int* bar) {
  __threadfence();
  __syncthreads();
  if (threadIdx.x == 0) {
    int g = __hip_atomic_load(bar + 1, __ATOMIC_RELAXED, __HIP_MEMORY_SCOPE_AGENT);
    int old = __hip_atomic_fetch_add(bar, 1, __ATOMIC_ACQ_REL, __HIP_MEMORY_SCOPE_AGENT);
    if (old == 255) {
      __hip_atomic_store(bar, 0, __ATOMIC_RELAXED, __HIP_MEMORY_SCOPE_AGENT);
      __hip_atomic_fetch_add(bar + 1, 1, __ATOMIC_RELEASE, __HIP_MEMORY_SCOPE_AGENT);
    } else {
      while (__hip_atomic_load(bar + 1, __ATOMIC_ACQUIRE, __HIP_MEMORY_SCOPE_AGENT) == g)
        __builtin_amdgcn_s_sleep(2);
    }
  }
  __syncthreads();
  __threadfence();
}

__launch_bounds__(256)
__global__ void seq_decoder(const float* __restrict__ enc,      // [32][128][512]
                            const float* __restrict__ enc_hid,  // [32][512]
                            const float* __restrict__ P,        // [32][128][512]
                            const float* __restrict__ emb_gx,   // [4096][1536] (incl b_ih)
                            const float* __restrict__ W_ih,     // [1536][1024]
                            const float* __restrict__ W_hh,     // [1536][512]
                            const float* __restrict__ b_hh,     // [1536]
                            float* __restrict__ h_buf,          // [2][32][512]
                            float* __restrict__ ctx_sum,        // [2][32][520]
                            bf16* __restrict__ x_out,           // [4096][1024]
                            float* __restrict__ h_final,        // [32][512]
                            int* __restrict__ bar) {
  __shared__ __align__(16) char smem[134272];
  const int bi = blockIdx.x, tid = threadIdx.x;
  const int lane = tid & 63;
  const bool is_attn = (bi < 128);

  // ---- pre-loop init ----
  // zero both parities of ctx_sum: 2*32*520 = 33280 floats, 130 per block
  if (tid < 130) ctx_sum[bi * 130 + tid] = 0.f;

  int b_a = 0;
  float* Pq = (float*)smem;                 // [32][516] f32
  float* Eq = (float*)(smem + 66048);       // [32][516] f32
  float* hs = (float*)(smem + 132096);      // [512] f32
  float* wscr = (float*)(smem + 134144);    // [32] f32

  bf16* x_cat = (bf16*)smem;                // [32][1032] bf16
  float* Cscr = (float*)(smem + 66048);     // [2][16][16] f32
  float* bhh_s = (float*)(smem + 68096);    // [16] f32
  bf16x8 bfrag[8];
  int g_g = 0;

  if (is_attn) {
    b_a = bi >> 2;
    int q = bi & 3;
    const float* Psrc = P   + (size_t)(b_a * 128 + q * 32) * 512;
    const float* Esrc = enc + (size_t)(b_a * 128 + q * 32) * 512;
    for (int idx = tid * 4; idx < 16384; idx += 1024) {
      int s = idx >> 9, k = idx & 511;
      *(float4*)(Pq + s * 516 + k) = *(const float4*)(Psrc + idx);
      *(float4*)(Eq + s * 516 + k) = *(const float4*)(Esrc + idx);
    }
    if (q == 0)
      for (int k = tid; k < 512; k += 256) h_buf[b_a * 512 + k] = enc_hid[b_a * 512 + k];
  } else {
    g_g = bi - 128;
    // build persistent B-fragments: 16 rows = 4 j's x {r, z, n_x, n_h}
    int wv = tid >> 6, n = lane & 15, qd = lane >> 4;
    int jl = n >> 2, gt = n & 3, jj = g_g * 4 + jl;
    for (int kk = 0; kk < 8; ++kk) {
      int ks = wv * 8 + kk;
      for (int j = 0; j < 8; ++j) {
        int k = ks * 32 + qd * 8 + j;
        float v;
        if (k < 512) {  // context half -> W_ih[:, 512+k]
          int row = (gt == 0) ? jj : (gt == 1) ? jj + 512 : (gt == 2) ? jj + 1024 : -1;
          v = (row < 0) ? 0.f : W_ih[(size_t)row * 1024 + 512 + k];
        } else {        // h half -> W_hh[:, k-512]
          int row = (gt == 0) ? jj : (gt == 1) ? jj + 512 : (gt == 3) ? jj + 1024 : -1;
          v = (row < 0) ? 0.f : W_hh[(size_t)row * 512 + (k - 512)];
        }
        bfrag[kk][j] = (bf16)v;
      }
    }
    if (tid < 16) {
      int jl2 = tid >> 2, g2 = tid & 3, j2 = g_g * 4 + jl2;
      bhh_s[tid] = (g2 == 0) ? b_hh[j2] : (g2 == 1) ? b_hh[j2 + 512]
                 : (g2 == 3) ? b_hh[j2 + 1024] : 0.f;
    }
  }
  gsync(bar);

  // ---- time loop ----
  for (int t = 0; t < T_; ++t) {
    const int p = t & 1;
    if (is_attn) {
      // load h_b to LDS
      if (tid < 128) *(float4*)(hs + tid * 4) = *(const float4*)(h_buf + p * 16384 + b_a * 512 + tid * 4);
      __syncthreads();
      // energies: 32 s per block, 8 threads each
      int s = tid >> 3, i = tid & 7;
      const float* Ps = Pq + s * 516 + i * 64;
      const float* hb = hs + i * 64;
      float4 a4 = {0.f, 0.f, 0.f, 0.f};
      for (int c = 0; c < 16; ++c) {
        int c2 = ((c + tid) & 15) * 4;
        float4 hv = *(const float4*)(hb + c2);
        float4 pv = *(const float4*)(Ps + c2);
        a4.x += hv.x * pv.x; a4.y += hv.y * pv.y;
        a4.z += hv.z * pv.z; a4.w += hv.w * pv.w;
      }
      float e = a4.x + a4.y + a4.z + a4.w;
      e += __shfl_xor(e, 1); e += __shfl_xor(e, 2); e += __shfl_xor(e, 4);
      if (i == 0) wscr[s] = __expf(fminf(e, 80.f));
      __syncthreads();
      if (tid == 0) {
        float l = 0.f;
        for (int ss = 0; ss < 32; ++ss) l += wscr[ss];
        atomicAdd(ctx_sum + p * 16640 + b_a * 520 + 512, l);
      }
      {
        int k2 = tid * 2;
        float a0 = 0.f, a1 = 0.f;
        for (int ss = 0; ss < 32; ++ss) {
          int sw = (ss + (tid >> 3)) & 31;
          float w = wscr[sw];
          float2 ev = *(const float2*)(Eq + sw * 516 + k2);
          a0 += w * ev.x; a1 += w * ev.y;
        }
        atomicAdd(ctx_sum + p * 16640 + b_a * 520 + k2, a0);
        atomicAdd(ctx_sum + p * 16640 + b_a * 520 + k2 + 1, a1);
      }
    } else {
      // zero other-parity accumulator for next step
      if (tid < 130) ctx_sum[(1 - p) * 16640 + g_g * 130 + tid] = 0.f;
    }
    gsync(bar);  // #1: context numerators complete

    if (!is_attn) {
      // phase A: build x_cat = [context | h] in LDS (bf16)
      for (int idx = tid; idx < 16384; idx += 256) {
        int b = idx >> 9, k = idx & 511;
        float l = ctx_sum[p * 16640 + b * 520 + 512] + 1e-35f;
        float c = ctx_sum[p * 16640 + b * 520 + k] / l;
        x_cat[b * 1032 + k] = (bf16)c;
        x_cat[b * 1032 + 512 + k] = (bf16)h_buf[p * 16384 + b * 512 + k];
      }
      if (tid < 128) {  // this block's 4 context columns of x_out
        int b = tid >> 2, kk = g_g * 4 + (tid & 3);
        float l = ctx_sum[p * 16640 + b * 520 + 512] + 1e-35f;
        float c = ctx_sum[p * 16640 + b * 520 + kk] / l;
        x_out[(size_t)(b * 128 + t) * 1024 + 512 + kk] = (bf16)c;
      }
      if (tid < 128) *(float4*)(Cscr + tid * 4) = make_float4(0.f, 0.f, 0.f, 0.f);
      __syncthreads();

      // phase B: MFMA, K split over 4 waves
      int wv = tid >> 6, m = lane & 15, qd = lane >> 4;
      f32x4 acc0 = {0.f, 0.f, 0.f, 0.f}, acc1 = {0.f, 0.f, 0.f, 0.f};
      for (int kk = 0; kk < 8; ++kk) {
        int ks = wv * 8 + kk;
        bf16x8 a0 = *(const bf16x8*)&x_cat[m * 1032 + ks * 32 + qd * 8];
        bf16x8 a1 = *(const bf16x8*)&x_cat[(m + 16) * 1032 + ks * 32 + qd * 8];
        acc0 = __builtin_amdgcn_mfma_f32_16x16x32_bf16(a0, bfrag[kk], acc0, 0, 0, 0);
        acc1 = __builtin_amdgcn_mfma_f32_16x16x32_bf16(a1, bfrag[kk], acc1, 0, 0, 0);
      }
      for (int r = 0; r < 4; ++r) {
        atomicAdd(&Cscr[(qd * 4 + r) * 16 + m], acc0[r]);
        atomicAdd(&Cscr[256 + (qd * 4 + r) * 16 + m], acc1[r]);
      }
      __syncthreads();

      // phase C: gates + h update (128 items: 32 b x 4 j)
      if (tid < 128) {
        int b = tid & 31, jl = tid >> 5;
        int tile = b >> 4, mr = b & 15;
        float Cr  = Cscr[tile * 256 + mr * 16 + jl * 4 + 0];
        float Cz  = Cscr[tile * 256 + mr * 16 + jl * 4 + 1];
        float Cnx = Cscr[tile * 256 + mr * 16 + jl * 4 + 2];
        float Cnh = Cscr[tile * 256 + mr * 16 + jl * 4 + 3];
        int jj = g_g * 4 + jl;
        size_t row = (size_t)b * 128 + t;
        float er = emb_gx[row * 1536 + jj];
        float ez = emb_gx[row * 1536 + 512 + jj];
        float en = emb_gx[row * 1536 + 1024 + jj];
        float hold = h_buf[p * 16384 + b * 512 + jj];
        float rg = 1.f / (1.f + __expf(-(er + bhh_s[jl * 4 + 0] + Cr)));
        float zg = 1.f / (1.f + __expf(-(ez + bhh_s[jl * 4 + 1] + Cz)));
        float hn = bhh_s[jl * 4 + 3] + Cnh;
        float ng = tanhf(en + Cnx + rg * hn);
        float hnew = (1.f - zg) * ng + zg * hold;
        h_buf[(1 - p) * 16384 + b * 512 + jj] = hnew;
        x_out[row * 1024 + jj] = (bf16)hnew;
        if (t == 127) h_final[b * 512 + jj] = hnew;
      }
    }
    gsync(bar);  // #2: h_new complete
  }
}

// ---------------------------------------------------------------------------
extern "C" void kernel_launch(void* const* d_in, const int* in_sizes, int n_in,
                              void* d_out, int out_size, void* d_ws, size_t ws_size,
                              hipStream_t stream) {
  (void)in_sizes; (void)n_in; (void)out_size; (void)ws_size;
  const float* enc   = (const float*)d_in[0];
  const float* ehid  = (const float*)d_in[1];
  const int*   tgt   = (const int*)d_in[2];
  const float* emb   = (const float*)d_in[3];
  const float* Wattn = (const float*)d_in[4];
  const float* Wih   = (const float*)d_in[5];
  const float* Whh   = (const float*)d_in[6];
  const float* bih   = (const float*)d_in[7];
  const float* bhh   = (const float*)d_in[8];
  const float* Wout  = (const float*)d_in[9];
  const float* bout  = (const float*)d_in[10];
  float* out = (float*)d_out;

  char* ws = (char*)d_ws;
  float* P      = (float*)(ws + 0);            // 8,388,608  B
  float* emb_gx = (float*)(ws + 8388608);      // 25,165,824 B
  bf16*  Xb     = (bf16*) (ws + 33554432);     // 4,194,304  B
  bf16*  encb   = (bf16*) (ws + 37748736);     // 4,194,304  B
  bf16*  WattnT = (bf16*) (ws + 41943040);     // 524,288    B
  bf16*  Wihb   = (bf16*) (ws + 42467328);     // 3,145,728  B
  bf16*  Woutb  = (bf16*) (ws + 45613056);     // 65,536,000 B
  bf16*  x_out  = (bf16*) (ws + 111149056);    // 8,388,608  B
  float* h_buf  = (float*)(ws + 119537664);    // 131,072    B
  float* ctxs   = (float*)(ws + 119668736);    // 133,120    B
  int*   bar    = (int*)  (ws + 119801856);    // 256        B

  hipMemsetAsync(bar, 0, 256, stream);

  cvt_bf16<<<2097152 / 1024, 256, 0, stream>>>(enc, encb, 2097152);
  cvt_bf16<<<1572864 / 1024, 256, 0, stream>>>(Wih, Wihb, 1572864);
  cvt_bf16<<<32768000 / 1024, 256, 0, stream>>>(Wout, Woutb, 32768000);
  transpose_cvt<<<1024, 256, 0, stream>>>(Wattn, WattnT);
  gather_emb<<<4096, 128, 0, stream>>>(emb, tgt, Xb);

  // P = enc @ W_attn      : [4096,512] x [512,512]
  gemm_bt<<<dim3(4, 32), 256, 0, stream>>>(encb, 512, WattnT, 512, P, 512, nullptr, 512);
  // emb_gx = X @ W_ih[:, :512]^T + b_ih : [4096,512] x [1536,512(ld 1024)]
  gemm_bt<<<dim3(12, 32), 256, 0, stream>>>(Xb, 512, Wihb, 1024, emb_gx, 1536, bih, 512);

  seq_decoder<<<256, 256, 0, stream>>>(enc, ehid, P, emb_gx, Wih, Whh, bhh,
                                       h_buf, ctxs, x_out, out + 131072000LL, bar);

  // logits = x_out @ W_out^T + b_out : [4096,1024] x [32000,1024]
  gemm_bt<<<dim3(250, 32), 256, 0, stream>>>(x_out, 1024, Woutb, 1024, out, 32000, bout, 1024);
}